// Round 16
// baseline (587.063 us; speedup 1.0000x reference)
//
#include <hip/hip_runtime.h>

// GWNet on MI355X — round 16.
// - Layer-2 attn kz 2->4: 512 attn blocks/launch = 2 blocks/CU (was 1/CU,
//   which made attn the launch-binding pole at ~140 µs; round-10 standalone
//   data shows ~98 µs/slice at 2/CU). heads merges 4 partials.
// - T1/T2 stored bf16 (cheb out -> head in): -72 MB stream traffic.
// - Everything else = round 15 (co-schedule, TOP-barrier loop, cvt_pk,
//   consolidated prep, MFMA heads).

#define NN 8192
#define NNZE 131072
#define CSHIFT 48.0f

typedef float4 f4;
typedef __attribute__((ext_vector_type(8))) short bf16x8;
typedef __attribute__((ext_vector_type(4))) float f32x4;

typedef __attribute__((address_space(3))) short lds_short;
typedef __attribute__((address_space(1))) const short glb_short;

struct P8s { short* p[8]; };

__device__ inline short f2b(float x){
  unsigned u = __float_as_uint(x);
  unsigned r = (u + 0x7fffu + ((u >> 16) & 1u)) >> 16;
  return (short)r;
}
__device__ inline float b2f(unsigned short b){
  return __uint_as_float(((unsigned)b) << 16);
}

// ---------------- prep A: [count A1 | count A2 | Z->bf16] ----------------
__global__ __launch_bounds__(256) void k_pre1(const int* __restrict__ i1, const int* __restrict__ i2,
                                              int* __restrict__ c1, int* __restrict__ c2,
                                              const float* __restrict__ Z, short* __restrict__ Zb){
  int e = blockIdx.x*256 + threadIdx.x;
  if (blockIdx.y == 0)      atomicAdd(&c1[i1[e]], 1);
  else if (blockIdx.y == 1) atomicAdd(&c2[i2[e]], 1);
  else {
    #pragma unroll
    for (int q=0;q<4;q++){ int i = q*NNZE + e; Zb[i] = f2b(Z[i]); }
  }
}

__global__ __launch_bounds__(1024) void k_scan2(const int* __restrict__ cnt1, const int* __restrict__ cnt2,
                                                int* __restrict__ ptr1, int* __restrict__ ptr2,
                                                int* __restrict__ cur1, int* __restrict__ cur2){
  __shared__ int sums[1024];
  const int* cnt = blockIdx.x ? cnt2 : cnt1;
  int* ptr = blockIdx.x ? ptr2 : ptr1;
  int* cur = blockIdx.x ? cur2 : cur1;
  int t = threadIdx.x;
  int loc[8]; int s = 0;
  #pragma unroll
  for (int i=0;i<8;i++){ loc[i]=s; s += cnt[t*8+i]; }
  sums[t]=s; __syncthreads();
  for (int off=1; off<1024; off<<=1){
    int v = (t>=off) ? sums[t-off] : 0;
    __syncthreads();
    sums[t] += v;
    __syncthreads();
  }
  int excl = sums[t]-s;
  #pragma unroll
  for (int i=0;i<8;i++){ int v = excl + loc[i]; ptr[t*8+i] = v; cur[t*8+i] = v; }
  if (t==1023) ptr[NN] = sums[1023];
}

// ---------------- prep B: [fill A1 | fill A2 | colsum | transb | wt] ----------------
__global__ __launch_bounds__(512) void k_pre3(
    const int* __restrict__ i1, const float* __restrict__ v1,
    const int* __restrict__ i2, const float* __restrict__ v2,
    int* __restrict__ cur1, int* __restrict__ cur2,
    int* __restrict__ cidx1, float* __restrict__ cval1,
    int* __restrict__ cidx2, float* __restrict__ cval2,
    const short* __restrict__ Zb, float* __restrict__ sbv,
    const float* __restrict__ X, short* __restrict__ XT1b,
    const float* __restrict__ W1, const float* __restrict__ W2,
    short* __restrict__ W1t, short* __restrict__ W2t)
{
  __shared__ float tile[32][33];
  int bx = blockIdx.x, t = threadIdx.x;
  if (bx < 512){
    const int* idx; const float* vals; int* cur; int* cidx; float* cval; int e;
    if (bx < 256){ idx=i1; vals=v1; cur=cur1; cidx=cidx1; cval=cval1; e = bx*512 + t; }
    else         { idx=i2; vals=v2; cur=cur2; cidx=cidx2; cval=cval2; e = (bx-256)*512 + t; }
    int r = idx[e], c = idx[NNZE+e];
    int p = atomicAdd(&cur[r], 1);
    cidx[p] = c; cval[p] = vals[e];
  } else if (bx < 1024){
    int cid = bx - 512;
    int jblk = cid & 63, iblk = cid >> 6;
    int w = t >> 6, l = t & 63;
    int lo = l & 15, g = l >> 4;
    int j = jblk*128 + w*16 + lo;
    const bf16x8* Zb8 = (const bf16x8*)Zb;
    bf16x8 bj0 = Zb8[j*8 + g];
    bf16x8 bj1 = Zb8[j*8 + g + 4];
    int i0 = iblk * (NN/8);
    float sum = 0.f;
    for (int i = i0; i < i0 + NN/8; i += 16){
      bf16x8 a0 = Zb8[(size_t)(i+lo)*8 + g];
      bf16x8 a1 = Zb8[(size_t)(i+lo)*8 + g + 4];
      f32x4 s = (f32x4){0.f,0.f,0.f,0.f};
      s = __builtin_amdgcn_mfma_f32_16x16x32_bf16(a0, bj0, s, 0,0,0);
      s = __builtin_amdgcn_mfma_f32_16x16x32_bf16(a1, bj1, s, 0,0,0);
      #pragma unroll
      for (int r=0;r<4;r++) sum += __expf(s[r] - CSHIFT);
    }
    sum += __shfl_xor(sum, 16);
    sum += __shfl_xor(sum, 32);
    if (g == 0) atomicAdd(sbv + j, sum);
  } else if (bx < 5120){
    int tid = bx - 1024;
    int j0 = (tid & 255)*32, f0 = (tid >> 8)*32;
    int tx = t & 31, ty = t >> 5;
    #pragma unroll
    for (int u=0;u<32;u+=16) tile[ty+u][tx] = X[(size_t)(f0+ty+u)*NN + j0+tx];
    __syncthreads();
    #pragma unroll
    for (int u=0;u<32;u+=16) XT1b[(size_t)(j0+ty+u)*512 + f0+tx] = f2b(tile[tx][ty+u]);
  } else if (bx == 5120){
    for (int i=t; i<64*128; i+=512){ int k=i>>7, o=i&127; W1t[o*64+k] = f2b(W1[i]); }
  } else {
    for (int i=t; i<128*128; i+=512){ int k=i>>7, o=i&127; W2t[o*128+k] = f2b(W2[i]); }
  }
}

// ---------------- layer-1 Yt: Yt[f][node] = bf16(X[f][node] / s[node]) ----------------
__global__ __launch_bounds__(256) void k_scaleb(const float* __restrict__ X, const float* __restrict__ sbv,
                                                short* __restrict__ Yt){
  int i = blockIdx.x*256 + threadIdx.x;
  int node4 = i & (NN/4 - 1);
  f4 x = ((const f4*)X)[i];
  f4 sv = ((const f4*)sbv)[node4];
  short4 o;
  o.x = f2b(x.x*(1.0f/sv.x)); o.y = f2b(x.y*(1.0f/sv.y));
  o.z = f2b(x.z*(1.0f/sv.z)); o.w = f2b(x.w*(1.0f/sv.w));
  ((short4*)Yt)[i] = o;
}

// ---------------- fused: [attn blocks | gather blocks] ----------------
// MODE 0 gather = dual spmm (bf16 out); MODE 1 gather = cheb (bf16 out).
template<int F, int MODE>
__global__ __launch_bounds__(512, 4) void k_fused(
    const short* __restrict__ Zb, const short* __restrict__ YS, P8s pp, int ksize, int kzbase, int nattn,
    const int* __restrict__ ptr1, const int* __restrict__ cidx1, const float* __restrict__ cval1,
    const int* __restrict__ ptr2, const int* __restrict__ cidx2, const float* __restrict__ cval2,
    const short* __restrict__ g1, const short* __restrict__ g2, const short* __restrict__ gy,
    short* __restrict__ so1, short* __restrict__ so2, short* __restrict__ Tb)
{
  __shared__ __align__(16) short zk[2][32*64];
  __shared__ __align__(16) short yt[2][256*32];
  __shared__ __align__(16) short p_lds[128*40];
  int t = threadIdx.x;

  if ((int)blockIdx.x < nattn){
    // ================= attention path =================
    constexpr int NBY = F/256;
    int id0 = blockIdx.x;
    int id = (id0 & 7)*(nattn >> 3) + (id0 >> 3);   // XCD-bijective (nattn % 8 == 0)
    int bx = id & 63, rest = id >> 6;
    int m0 = bx * 128;
    int n0 = (rest % NBY) * 256;
    int kz = kzbase + rest / NBY;
    int kbeg = kz * ksize, kend = kbeg + ksize;
    int w = t >> 6, l = t & 63;
    int lo = l & 15, g = l >> 4;
    int wm = w >> 2, wn = w & 3;

    const bf16x8* Zb8 = (const bf16x8*)Zb;
    int zirow = m0 + w*16 + lo;
    bf16x8 ziA0 = Zb8[(size_t)zirow*8 + g];
    bf16x8 ziA1 = Zb8[(size_t)zirow*8 + g + 4];

    f32x4 acc[4][4];
    #pragma unroll
    for (int i=0;i<4;i++)
      #pragma unroll
      for (int j=0;j<4;j++) acc[i][j] = (f32x4){0.f,0.f,0.f,0.f};

    auto STAGE = [&](int b, int kk){
      if (t < 256){
        int r = t >> 3, c = t & 7;
        const short* src = Zb + (((size_t)(kk + r)) << 6) + ((c ^ (r & 7)) << 3);
        __builtin_amdgcn_global_load_lds((glb_short*)src, (lds_short*)&zk[b][t*8], 16, 0, 0);
      }
      #pragma unroll
      for (int p=0;p<2;p++){
        int cc = p*512 + t;
        int r = cc >> 2, c = cc & 3;
        const short* src = YS + (size_t)(n0 + r)*NN + kk + ((c ^ ((r >> 1) & 3)) << 3);
        __builtin_amdgcn_global_load_lds((glb_short*)src, (lds_short*)&yt[b][cc*8], 16, 0, 0);
      }
    };

    STAGE(0, kbeg);

    int cur = 0;
    for (int k0 = kbeg; k0 < kend; k0 += 32){
      asm volatile("s_waitcnt vmcnt(0)" ::: "memory");
      __builtin_amdgcn_s_barrier();
      __builtin_amdgcn_sched_barrier(0);
      if (k0 + 32 < kend) STAGE(cur ^ 1, k0 + 32);
      // ---- S phase ----
      int xa = g ^ (lo & 7), xb = (g + 4) ^ (lo & 7);
      bf16x8 b00 = *(const bf16x8*)&zk[cur][(lo*8 + xa)*8];
      bf16x8 b01 = *(const bf16x8*)&zk[cur][(lo*8 + xb)*8];
      bf16x8 b10 = *(const bf16x8*)&zk[cur][((16+lo)*8 + xa)*8];
      bf16x8 b11 = *(const bf16x8*)&zk[cur][((16+lo)*8 + xb)*8];
      f32x4 s0 = (f32x4){0.f,0.f,0.f,0.f};
      f32x4 s1 = (f32x4){0.f,0.f,0.f,0.f};
      s0 = __builtin_amdgcn_mfma_f32_16x16x32_bf16(ziA0, b00, s0, 0,0,0);
      s0 = __builtin_amdgcn_mfma_f32_16x16x32_bf16(ziA1, b01, s0, 0,0,0);
      s1 = __builtin_amdgcn_mfma_f32_16x16x32_bf16(ziA0, b10, s1, 0,0,0);
      s1 = __builtin_amdgcn_mfma_f32_16x16x32_bf16(ziA1, b11, s1, 0,0,0);
      int prow = w*16 + g*4;
      #pragma unroll
      for (int r=0;r<4;r++){
        float e0f = __expf(s0[r] - CSHIFT);
        float e1f = __expf(s1[r] - CSHIFT);
        unsigned u;
        asm("v_cvt_pk_bf16_f32 %0, %1, %2" : "=v"(u) : "v"(e0f), "v"(e1f));
        p_lds[(prow+r)*40 + lo]      = (short)(u & 0xffffu);
        p_lds[(prow+r)*40 + 16 + lo] = (short)(u >> 16);
      }
      asm volatile("s_waitcnt lgkmcnt(0)" ::: "memory");
      __builtin_amdgcn_s_barrier();
      // ---- PV phase ----
      bf16x8 aP[4];
      #pragma unroll
      for (int mf=0; mf<4; mf++)
        aP[mf] = *(const bf16x8*)&p_lds[(wm*64 + mf*16 + lo)*40 + g*8];
      __builtin_amdgcn_s_setprio(1);
      #pragma unroll
      for (int nf=0; nf<4; nf++){
        int nl = wn*64 + nf*16 + lo;
        bf16x8 bY = *(const bf16x8*)&yt[cur][(nl*4 + (g ^ ((nl >> 1) & 3)))*8];
        #pragma unroll
        for (int mf=0; mf<4; mf++)
          acc[mf][nf] = __builtin_amdgcn_mfma_f32_16x16x32_bf16(aP[mf], bY, acc[mf][nf], 0,0,0);
      }
      __builtin_amdgcn_s_setprio(0);
      cur ^= 1;
    }
    short* outp = pp.p[kz];
    #pragma unroll
    for (int mf=0; mf<4; mf++){
      int row = m0 + wm*64 + mf*16 + g*4;
      #pragma unroll
      for (int nf=0; nf<4; nf++){
        int col = n0 + wn*64 + nf*16 + lo;
        #pragma unroll
        for (int r=0;r<4;r++)
          outp[(size_t)(row+r)*F + col] = f2b(acc[mf][nf][r]);
      }
    }
  } else {
    // ================= gather path (8-deep unroll) =================
    constexpr int LPR = F/8;
    constexpr int RPB = 512/LPR;
    int gid = blockIdx.x - nattn;
    int ts = t % LPR, rl = t / LPR;
    if (MODE == 0){
      constexpr int M = NN/RPB;
      int mat = gid / M;
      int blk = gid - mat*M;
      const int*   ptr  = mat ? ptr2  : ptr1;
      const int*   cidx = mat ? cidx2 : cidx1;
      const float* cval = mat ? cval2 : cval1;
      short* outb = mat ? so2 : so1;
      int r = blk*RPB + rl;
      const bf16x8* Y8 = (const bf16x8*)g1;
      int p0 = ptr[r], p1 = ptr[r+1];
      float a[8];
      #pragma unroll
      for (int j=0;j<8;j++) a[j]=0.f;
      int p = p0;
      for (; p+7 < p1; p += 8){
        int   c[8]; float v[8]; bf16x8 x[8];
        #pragma unroll
        for (int q=0;q<8;q++){ c[q]=cidx[p+q]; v[q]=cval[p+q]; }
        #pragma unroll
        for (int q=0;q<8;q++) x[q] = Y8[(size_t)c[q]*LPR + ts];
        #pragma unroll
        for (int q=0;q<8;q++)
          #pragma unroll
          for (int j=0;j<8;j++) a[j] += v[q]*b2f((unsigned short)x[q][j]);
      }
      for (; p < p1; ++p){
        int c0 = cidx[p]; float v0 = cval[p];
        bf16x8 x0 = Y8[(size_t)c0*LPR + ts];
        #pragma unroll
        for (int j=0;j<8;j++) a[j] += v0*b2f((unsigned short)x0[j]);
      }
      bf16x8 o;
      #pragma unroll
      for (int j=0;j<8;j++) o[j] = f2b(a[j]);
      ((bf16x8*)outb)[(size_t)r*LPR + ts] = o;
    } else {
      int r = gid*RPB + rl;
      const bf16x8* Xa = (const bf16x8*)g1;
      const bf16x8* Xb = (const bf16x8*)g2;
      float a[8];
      #pragma unroll
      for (int j=0;j<8;j++) a[j]=0.f;
      {
        int p0 = ptr1[r], p1 = ptr1[r+1];
        int p = p0;
        for (; p+7 < p1; p += 8){
          int   c[8]; float v[8]; bf16x8 x[8];
          #pragma unroll
          for (int q=0;q<8;q++){ c[q]=cidx1[p+q]; v[q]=cval1[p+q]; }
          #pragma unroll
          for (int q=0;q<8;q++) x[q] = Xa[(size_t)c[q]*LPR + ts];
          #pragma unroll
          for (int q=0;q<8;q++)
            #pragma unroll
            for (int j=0;j<8;j++) a[j] += v[q]*b2f((unsigned short)x[q][j]);
        }
        for (; p < p1; ++p){
          int c0 = cidx1[p]; float v0 = cval1[p];
          bf16x8 x0 = Xa[(size_t)c0*LPR + ts];
          #pragma unroll
          for (int j=0;j<8;j++) a[j] += v0*b2f((unsigned short)x0[j]);
        }
      }
      {
        int p0 = ptr2[r], p1 = ptr2[r+1];
        int p = p0;
        for (; p+7 < p1; p += 8){
          int   c[8]; float v[8]; bf16x8 x[8];
          #pragma unroll
          for (int q=0;q<8;q++){ c[q]=cidx2[p+q]; v[q]=cval2[p+q]; }
          #pragma unroll
          for (int q=0;q<8;q++) x[q] = Xb[(size_t)c[q]*LPR + ts];
          #pragma unroll
          for (int q=0;q<8;q++)
            #pragma unroll
            for (int j=0;j<8;j++) a[j] += v[q]*b2f((unsigned short)x[q][j]);
        }
        for (; p < p1; ++p){
          int c0 = cidx2[p]; float v0 = cval2[p];
          bf16x8 x0 = Xb[(size_t)c0*LPR + ts];
          #pragma unroll
          for (int j=0;j<8;j++) a[j] += v0*b2f((unsigned short)x0[j]);
        }
      }
      bf16x8 sa = Xa[(size_t)r*LPR + ts];
      bf16x8 sbx = Xb[(size_t)r*LPR + ts];
      bf16x8 yv = ((const bf16x8*)gy)[(size_t)r*LPR + ts];
      bf16x8 ob;
      #pragma unroll
      for (int j=0;j<8;j++)
        ob[j] = f2b(2.f*a[j] + b2f((unsigned short)sa[j]) + b2f((unsigned short)sbx[j]) - b2f((unsigned short)yv[j]));
      ((bf16x8*)Tb)[(size_t)r*LPR + ts] = ob;
    }
  }
}

// ---------------- layer-1 head (MFMA, 4 partials, bf16 T): H=relu((T+Σp)W1), + layer-2 Yt ----------------
__global__ __launch_bounds__(512) void k_headm_mfma(
    const short* __restrict__ Tb, P8s parts, const short* __restrict__ W1t,
    const float* __restrict__ sbv, short* __restrict__ Hb, short* __restrict__ Yt)
{
  __shared__ __align__(16) short hl[128*136];
  __shared__ float rsl[128];
  int t = threadIdx.x;
  int j0 = blockIdx.x*128, b = blockIdx.y;
  for (int u = t; u < 1024; u += 512){
    int row = u >> 3, c = u & 7;
    size_t base = (size_t)(j0+row)*512 + b*64 + c*8;
    bf16x8 tb = *(const bf16x8*)(Tb + base);
    float v[8];
    #pragma unroll
    for (int q=0;q<8;q++) v[q] = b2f((unsigned short)tb[q]);
    #pragma unroll
    for (int j=0;j<4;j++){
      bf16x8 p = *(const bf16x8*)(parts.p[j] + base);
      #pragma unroll
      for (int q=0;q<8;q++) v[q] += b2f((unsigned short)p[q]);
    }
    bf16x8 o;
    #pragma unroll
    for (int q=0;q<8;q++) o[q] = f2b(v[q]);
    *(bf16x8*)&hl[(row*8 + (c ^ (row & 7)))*8] = o;
  }
  if (t < 128) rsl[t] = 1.0f / sbv[j0 + t];
  __syncthreads();
  int w = t >> 6, l = t & 63, lo = l & 15, g = l >> 4;
  int arow = w*16 + lo;
  f32x4 acc[8];
  #pragma unroll
  for (int nf=0;nf<8;nf++) acc[nf] = (f32x4){0.f,0.f,0.f,0.f};
  #pragma unroll
  for (int ks=0; ks<2; ks++){
    bf16x8 aA = *(const bf16x8*)&hl[(arow*8 + ((ks*4+g) ^ (arow & 7)))*8];
    #pragma unroll
    for (int nf=0; nf<8; nf++){
      bf16x8 bW = *(const bf16x8*)(W1t + (size_t)(nf*16+lo)*64 + ks*32 + g*8);
      acc[nf] = __builtin_amdgcn_mfma_f32_16x16x32_bf16(aA, bW, acc[nf], 0,0,0);
    }
  }
  __syncthreads();
  int m = w*16 + g*4;
  #pragma unroll
  for (int nf=0; nf<8; nf++){
    int o = nf*16 + lo;
    #pragma unroll
    for (int r=0;r<4;r++){
      short hv = f2b(fmaxf(acc[nf][r], 0.f));
      hl[o*136 + m + r] = hv;
      Hb[(size_t)(j0+m+r)*1024 + b*128 + o] = hv;
    }
  }
  __syncthreads();
  for (int u = t; u < 2048; u += 512){
    int o = u >> 4, m8 = (u & 15)*8;
    bf16x8 hv = *(const bf16x8*)&hl[o*136 + m8];
    bf16x8 ov;
    #pragma unroll
    for (int q=0;q<8;q++) ov[q] = f2b(b2f((unsigned short)hv[q]) * rsl[m8+q]);
    *(bf16x8*)(Yt + (size_t)(b*128+o)*NN + j0 + m8) = ov;
  }
}

// ---------------- layer-2 head (MFMA, 4 partials, bf16 T) with fused node-mean ----------------
__global__ __launch_bounds__(512) void k_heads_mfma(
    const short* __restrict__ Tb, P8s parts, const short* __restrict__ W2t,
    float* __restrict__ out)
{
  __shared__ __align__(16) short al[128*16*8];
  __shared__ float red[8*128];
  int t = threadIdx.x;
  int j0 = blockIdx.x*128, b = blockIdx.y;
  for (int u = t; u < 2048; u += 512){
    int row = u >> 4, c = u & 15;
    size_t base = (size_t)(j0+row)*1024 + b*128 + c*8;
    bf16x8 tb = *(const bf16x8*)(Tb + base);
    float v[8];
    #pragma unroll
    for (int q=0;q<8;q++) v[q] = b2f((unsigned short)tb[q]);
    #pragma unroll
    for (int j=0;j<4;j++){
      bf16x8 p = *(const bf16x8*)(parts.p[j] + base);
      #pragma unroll
      for (int q=0;q<8;q++) v[q] += b2f((unsigned short)p[q]);
    }
    bf16x8 o;
    #pragma unroll
    for (int q=0;q<8;q++) o[q] = f2b(v[q]);
    *(bf16x8*)&al[(row*16 + (c ^ (row & 7)))*8] = o;
  }
  __syncthreads();
  int w = t >> 6, l = t & 63, lo = l & 15, g = l >> 4;
  int arow = w*16 + lo;
  f32x4 acc[8];
  #pragma unroll
  for (int nf=0;nf<8;nf++) acc[nf] = (f32x4){0.f,0.f,0.f,0.f};
  #pragma unroll
  for (int ks=0; ks<4; ks++){
    bf16x8 aA = *(const bf16x8*)&al[(arow*16 + ((ks*4+g) ^ (arow & 7)))*8];
    #pragma unroll
    for (int nf=0; nf<8; nf++){
      bf16x8 bW = *(const bf16x8*)(W2t + (size_t)(nf*16+lo)*128 + ks*32 + g*8);
      acc[nf] = __builtin_amdgcn_mfma_f32_16x16x32_bf16(aA, bW, acc[nf], 0,0,0);
    }
  }
  #pragma unroll
  for (int nf=0; nf<8; nf++){
    float s = fmaxf(acc[nf][0],0.f) + fmaxf(acc[nf][1],0.f)
            + fmaxf(acc[nf][2],0.f) + fmaxf(acc[nf][3],0.f);
    s += __shfl_xor(s, 16);
    s += __shfl_xor(s, 32);
    if (g == 0) red[w*128 + nf*16 + lo] = s;
  }
  __syncthreads();
  if (t < 128){
    float tot = 0.f;
    #pragma unroll
    for (int ww=0; ww<8; ww++) tot += red[ww*128 + t];
    atomicAdd(&out[b*128 + t], tot * (1.0f/8192.0f));
  }
}

// ---------------- launcher ----------------
extern "C" void kernel_launch(void* const* d_in, const int* in_sizes, int n_in,
                              void* d_out, int out_size, void* d_ws, size_t ws_size,
                              hipStream_t stream){
  const int*   A1i = (const int*)d_in[0];
  const float* A1v = (const float*)d_in[1];
  const int*   A2i = (const int*)d_in[2];
  const float* A2v = (const float*)d_in[3];
  const float* X   = (const float*)d_in[4];
  const float* Z   = (const float*)d_in[5];
  const float* W1  = (const float*)d_in[6];
  const float* W2  = (const float*)d_in[7];
  float* out = (float*)d_out;

  char* w = (char*)d_ws;
  size_t off = 0;
  auto alloc = [&](size_t b)->char* {
    char* p = w + off;
    off += (b + 1023) & ~(size_t)1023;
    return p;
  };
  const size_t MB = 1024*1024;
  float* sb    = (float*)alloc(NN*4);
  int*   ptr1  = (int*)  alloc((NN+1)*4);
  int*   ptr2  = (int*)  alloc((NN+1)*4);
  int*   cnt   = (int*)  alloc(2*NN*4);
  int*   cur1  = (int*)  alloc(NN*4);
  int*   cur2  = (int*)  alloc(NN*4);
  int*   cidx1 = (int*)  alloc(NNZE*4);
  float* cval1 = (float*)alloc(NNZE*4);
  int*   cidx2 = (int*)  alloc(NNZE*4);
  float* cval2 = (float*)alloc(NNZE*4);
  short* Zbf   = (short*)alloc((size_t)NN*64*2);
  short* W1t   = (short*)alloc(128*64*2);
  short* W2t   = (short*)alloc(128*128*2);
  short* XT1b  = (short*)alloc((size_t)NN*512*2);
  short* BUFA  = (short*)alloc((size_t)NN*1024*2);
  short* BUFB  = (short*)alloc((size_t)NN*1024*2);
  short* HTb   = (short*)alloc((size_t)NN*1024*2);
  short* YS    = (short*)alloc((size_t)NN*1024*2);
  short* T1b   = (short*)alloc((size_t)NN*512*2);    // bf16 now
  short* T2b   = (short*)alloc((size_t)NN*1024*2);   // bf16 now
  char*  PART  = alloc((size_t)64*MB);               // 4 x 16MB layer-2 partials
  (void)ws_size;
  int* cnt1 = cnt;
  int* cnt2 = cnt + NN;

  // prep chain
  hipMemsetAsync(cnt, 0, 2*NN*4, stream);
  hipMemsetAsync(sb, 0, NN*4, stream);
  hipMemsetAsync(out, 0, 1024*4, stream);
  k_pre1<<<dim3(NNZE/256, 3), 256, 0, stream>>>(A1i, A2i, cnt1, cnt2, Z, Zbf);
  k_scan2<<<2, 1024, 0, stream>>>(cnt1, cnt2, ptr1, ptr2, cur1, cur2);
  k_pre3<<<5122, 512, 0, stream>>>(A1i, A1v, A2i, A2v, cur1, cur2,
                                   cidx1, cval1, cidx2, cval2,
                                   Zbf, sb, X, XT1b, W1, W2, W1t, W2t);
  k_scaleb<<<512*NN/4/256, 256, 0, stream>>>(X, sb, YS);

  // ---- layer 1 (F=512, attn kz=4, 2 slices/launch = 256 blocks) ----
  P8s pp1{};
  for (int i=0;i<4;i++) pp1.p[i] = (short*)(PART + (size_t)i*8*MB);
  k_fused<512,0><<<256 + 2048, 512, 0, stream>>>(Zbf, YS, pp1, NN/4, 0, 256,
      ptr1, cidx1, cval1, ptr2, cidx2, cval2,
      XT1b, nullptr, nullptr, BUFA, BUFB, nullptr);
  k_fused<512,1><<<256 + 1024, 512, 0, stream>>>(Zbf, YS, pp1, NN/4, 2, 256,
      ptr1, cidx1, cval1, ptr2, cidx2, cval2,
      BUFA, BUFB, XT1b, nullptr, nullptr, T1b);
  k_headm_mfma<<<dim3(NN/128, 8), 512, 0, stream>>>(T1b, pp1, W1t, sb, HTb, YS);

  // ---- layer 2 (F=1024, attn kz=4, 2 slices/launch = 512 blocks = 2/CU) ----
  P8s pp2{};
  for (int i=0;i<4;i++) pp2.p[i] = (short*)(PART + (size_t)i*16*MB);
  k_fused<1024,0><<<512 + 4096, 512, 0, stream>>>(Zbf, YS, pp2, NN/4, 0, 512,
      ptr1, cidx1, cval1, ptr2, cidx2, cval2,
      HTb, nullptr, nullptr, BUFA, BUFB, nullptr);
  k_fused<1024,1><<<512 + 2048, 512, 0, stream>>>(Zbf, YS, pp2, NN/4, 2, 512,
      ptr1, cidx1, cval1, ptr2, cidx2, cval2,
      BUFA, BUFB, HTb, nullptr, nullptr, T2b);
  k_heads_mfma<<<dim3(NN/128, 8), 512, 0, stream>>>(T2b, pp2, W2t, out);
}

// Round 17
// 523.885 us; speedup vs baseline: 1.1206x; 1.1206x over previous
//
#include <hip/hip_runtime.h>

// GWNet on MI355X — round 17.
// - REVERT round-16's layer-2 kz 2->4 (regressed +57 µs: extra attn blocks
//   displaced co-resident gather blocks + doubled partial traffic; nattn=256
//   is the co-schedule balance optimum, bracketed by r14/r16 failures).
// - KEEP bf16 T1/T2 (heads read bf16 T; -72 MB streams).
// - Otherwise identical to round 15 (best: 530 µs).

#define NN 8192
#define NNZE 131072
#define CSHIFT 48.0f

typedef float4 f4;
typedef __attribute__((ext_vector_type(8))) short bf16x8;
typedef __attribute__((ext_vector_type(4))) float f32x4;

typedef __attribute__((address_space(3))) short lds_short;
typedef __attribute__((address_space(1))) const short glb_short;

struct P8s { short* p[8]; };

__device__ inline short f2b(float x){
  unsigned u = __float_as_uint(x);
  unsigned r = (u + 0x7fffu + ((u >> 16) & 1u)) >> 16;
  return (short)r;
}
__device__ inline float b2f(unsigned short b){
  return __uint_as_float(((unsigned)b) << 16);
}

// ---------------- prep A: [count A1 | count A2 | Z->bf16] ----------------
__global__ __launch_bounds__(256) void k_pre1(const int* __restrict__ i1, const int* __restrict__ i2,
                                              int* __restrict__ c1, int* __restrict__ c2,
                                              const float* __restrict__ Z, short* __restrict__ Zb){
  int e = blockIdx.x*256 + threadIdx.x;
  if (blockIdx.y == 0)      atomicAdd(&c1[i1[e]], 1);
  else if (blockIdx.y == 1) atomicAdd(&c2[i2[e]], 1);
  else {
    #pragma unroll
    for (int q=0;q<4;q++){ int i = q*NNZE + e; Zb[i] = f2b(Z[i]); }
  }
}

__global__ __launch_bounds__(1024) void k_scan2(const int* __restrict__ cnt1, const int* __restrict__ cnt2,
                                                int* __restrict__ ptr1, int* __restrict__ ptr2,
                                                int* __restrict__ cur1, int* __restrict__ cur2){
  __shared__ int sums[1024];
  const int* cnt = blockIdx.x ? cnt2 : cnt1;
  int* ptr = blockIdx.x ? ptr2 : ptr1;
  int* cur = blockIdx.x ? cur2 : cur1;
  int t = threadIdx.x;
  int loc[8]; int s = 0;
  #pragma unroll
  for (int i=0;i<8;i++){ loc[i]=s; s += cnt[t*8+i]; }
  sums[t]=s; __syncthreads();
  for (int off=1; off<1024; off<<=1){
    int v = (t>=off) ? sums[t-off] : 0;
    __syncthreads();
    sums[t] += v;
    __syncthreads();
  }
  int excl = sums[t]-s;
  #pragma unroll
  for (int i=0;i<8;i++){ int v = excl + loc[i]; ptr[t*8+i] = v; cur[t*8+i] = v; }
  if (t==1023) ptr[NN] = sums[1023];
}

// ---------------- prep B: [fill A1 | fill A2 | colsum | transb | wt] ----------------
__global__ __launch_bounds__(512) void k_pre3(
    const int* __restrict__ i1, const float* __restrict__ v1,
    const int* __restrict__ i2, const float* __restrict__ v2,
    int* __restrict__ cur1, int* __restrict__ cur2,
    int* __restrict__ cidx1, float* __restrict__ cval1,
    int* __restrict__ cidx2, float* __restrict__ cval2,
    const short* __restrict__ Zb, float* __restrict__ sbv,
    const float* __restrict__ X, short* __restrict__ XT1b,
    const float* __restrict__ W1, const float* __restrict__ W2,
    short* __restrict__ W1t, short* __restrict__ W2t)
{
  __shared__ float tile[32][33];
  int bx = blockIdx.x, t = threadIdx.x;
  if (bx < 512){
    const int* idx; const float* vals; int* cur; int* cidx; float* cval; int e;
    if (bx < 256){ idx=i1; vals=v1; cur=cur1; cidx=cidx1; cval=cval1; e = bx*512 + t; }
    else         { idx=i2; vals=v2; cur=cur2; cidx=cidx2; cval=cval2; e = (bx-256)*512 + t; }
    int r = idx[e], c = idx[NNZE+e];
    int p = atomicAdd(&cur[r], 1);
    cidx[p] = c; cval[p] = vals[e];
  } else if (bx < 1024){
    int cid = bx - 512;
    int jblk = cid & 63, iblk = cid >> 6;
    int w = t >> 6, l = t & 63;
    int lo = l & 15, g = l >> 4;
    int j = jblk*128 + w*16 + lo;
    const bf16x8* Zb8 = (const bf16x8*)Zb;
    bf16x8 bj0 = Zb8[j*8 + g];
    bf16x8 bj1 = Zb8[j*8 + g + 4];
    int i0 = iblk * (NN/8);
    float sum = 0.f;
    for (int i = i0; i < i0 + NN/8; i += 16){
      bf16x8 a0 = Zb8[(size_t)(i+lo)*8 + g];
      bf16x8 a1 = Zb8[(size_t)(i+lo)*8 + g + 4];
      f32x4 s = (f32x4){0.f,0.f,0.f,0.f};
      s = __builtin_amdgcn_mfma_f32_16x16x32_bf16(a0, bj0, s, 0,0,0);
      s = __builtin_amdgcn_mfma_f32_16x16x32_bf16(a1, bj1, s, 0,0,0);
      #pragma unroll
      for (int r=0;r<4;r++) sum += __expf(s[r] - CSHIFT);
    }
    sum += __shfl_xor(sum, 16);
    sum += __shfl_xor(sum, 32);
    if (g == 0) atomicAdd(sbv + j, sum);
  } else if (bx < 5120){
    int tid = bx - 1024;
    int j0 = (tid & 255)*32, f0 = (tid >> 8)*32;
    int tx = t & 31, ty = t >> 5;
    #pragma unroll
    for (int u=0;u<32;u+=16) tile[ty+u][tx] = X[(size_t)(f0+ty+u)*NN + j0+tx];
    __syncthreads();
    #pragma unroll
    for (int u=0;u<32;u+=16) XT1b[(size_t)(j0+ty+u)*512 + f0+tx] = f2b(tile[tx][ty+u]);
  } else if (bx == 5120){
    for (int i=t; i<64*128; i+=512){ int k=i>>7, o=i&127; W1t[o*64+k] = f2b(W1[i]); }
  } else {
    for (int i=t; i<128*128; i+=512){ int k=i>>7, o=i&127; W2t[o*128+k] = f2b(W2[i]); }
  }
}

// ---------------- layer-1 Yt: Yt[f][node] = bf16(X[f][node] / s[node]) ----------------
__global__ __launch_bounds__(256) void k_scaleb(const float* __restrict__ X, const float* __restrict__ sbv,
                                                short* __restrict__ Yt){
  int i = blockIdx.x*256 + threadIdx.x;
  int node4 = i & (NN/4 - 1);
  f4 x = ((const f4*)X)[i];
  f4 sv = ((const f4*)sbv)[node4];
  short4 o;
  o.x = f2b(x.x*(1.0f/sv.x)); o.y = f2b(x.y*(1.0f/sv.y));
  o.z = f2b(x.z*(1.0f/sv.z)); o.w = f2b(x.w*(1.0f/sv.w));
  ((short4*)Yt)[i] = o;
}

// ---------------- fused: [attn blocks | gather blocks] ----------------
template<int F, int MODE>
__global__ __launch_bounds__(512, 4) void k_fused(
    const short* __restrict__ Zb, const short* __restrict__ YS, P8s pp, int ksize, int kzbase, int nattn,
    const int* __restrict__ ptr1, const int* __restrict__ cidx1, const float* __restrict__ cval1,
    const int* __restrict__ ptr2, const int* __restrict__ cidx2, const float* __restrict__ cval2,
    const short* __restrict__ g1, const short* __restrict__ g2, const short* __restrict__ gy,
    short* __restrict__ so1, short* __restrict__ so2, short* __restrict__ Tb)
{
  __shared__ __align__(16) short zk[2][32*64];
  __shared__ __align__(16) short yt[2][256*32];
  __shared__ __align__(16) short p_lds[128*40];
  int t = threadIdx.x;

  if ((int)blockIdx.x < nattn){
    // ================= attention path =================
    constexpr int NBY = F/256;
    int id0 = blockIdx.x;
    int id = (id0 & 7)*(nattn >> 3) + (id0 >> 3);   // XCD-bijective (nattn % 8 == 0)
    int bx = id & 63, rest = id >> 6;
    int m0 = bx * 128;
    int n0 = (rest % NBY) * 256;
    int kz = kzbase + rest / NBY;
    int kbeg = kz * ksize, kend = kbeg + ksize;
    int w = t >> 6, l = t & 63;
    int lo = l & 15, g = l >> 4;
    int wm = w >> 2, wn = w & 3;

    const bf16x8* Zb8 = (const bf16x8*)Zb;
    int zirow = m0 + w*16 + lo;
    bf16x8 ziA0 = Zb8[(size_t)zirow*8 + g];
    bf16x8 ziA1 = Zb8[(size_t)zirow*8 + g + 4];

    f32x4 acc[4][4];
    #pragma unroll
    for (int i=0;i<4;i++)
      #pragma unroll
      for (int j=0;j<4;j++) acc[i][j] = (f32x4){0.f,0.f,0.f,0.f};

    auto STAGE = [&](int b, int kk){
      if (t < 256){
        int r = t >> 3, c = t & 7;
        const short* src = Zb + (((size_t)(kk + r)) << 6) + ((c ^ (r & 7)) << 3);
        __builtin_amdgcn_global_load_lds((glb_short*)src, (lds_short*)&zk[b][t*8], 16, 0, 0);
      }
      #pragma unroll
      for (int p=0;p<2;p++){
        int cc = p*512 + t;
        int r = cc >> 2, c = cc & 3;
        const short* src = YS + (size_t)(n0 + r)*NN + kk + ((c ^ ((r >> 1) & 3)) << 3);
        __builtin_amdgcn_global_load_lds((glb_short*)src, (lds_short*)&yt[b][cc*8], 16, 0, 0);
      }
    };

    STAGE(0, kbeg);

    int cur = 0;
    for (int k0 = kbeg; k0 < kend; k0 += 32){
      asm volatile("s_waitcnt vmcnt(0)" ::: "memory");
      __builtin_amdgcn_s_barrier();
      __builtin_amdgcn_sched_barrier(0);
      if (k0 + 32 < kend) STAGE(cur ^ 1, k0 + 32);
      // ---- S phase ----
      int xa = g ^ (lo & 7), xb = (g + 4) ^ (lo & 7);
      bf16x8 b00 = *(const bf16x8*)&zk[cur][(lo*8 + xa)*8];
      bf16x8 b01 = *(const bf16x8*)&zk[cur][(lo*8 + xb)*8];
      bf16x8 b10 = *(const bf16x8*)&zk[cur][((16+lo)*8 + xa)*8];
      bf16x8 b11 = *(const bf16x8*)&zk[cur][((16+lo)*8 + xb)*8];
      f32x4 s0 = (f32x4){0.f,0.f,0.f,0.f};
      f32x4 s1 = (f32x4){0.f,0.f,0.f,0.f};
      s0 = __builtin_amdgcn_mfma_f32_16x16x32_bf16(ziA0, b00, s0, 0,0,0);
      s0 = __builtin_amdgcn_mfma_f32_16x16x32_bf16(ziA1, b01, s0, 0,0,0);
      s1 = __builtin_amdgcn_mfma_f32_16x16x32_bf16(ziA0, b10, s1, 0,0,0);
      s1 = __builtin_amdgcn_mfma_f32_16x16x32_bf16(ziA1, b11, s1, 0,0,0);
      int prow = w*16 + g*4;
      #pragma unroll
      for (int r=0;r<4;r++){
        float e0f = __expf(s0[r] - CSHIFT);
        float e1f = __expf(s1[r] - CSHIFT);
        unsigned u;
        asm("v_cvt_pk_bf16_f32 %0, %1, %2" : "=v"(u) : "v"(e0f), "v"(e1f));
        p_lds[(prow+r)*40 + lo]      = (short)(u & 0xffffu);
        p_lds[(prow+r)*40 + 16 + lo] = (short)(u >> 16);
      }
      asm volatile("s_waitcnt lgkmcnt(0)" ::: "memory");
      __builtin_amdgcn_s_barrier();
      // ---- PV phase ----
      bf16x8 aP[4];
      #pragma unroll
      for (int mf=0; mf<4; mf++)
        aP[mf] = *(const bf16x8*)&p_lds[(wm*64 + mf*16 + lo)*40 + g*8];
      __builtin_amdgcn_s_setprio(1);
      #pragma unroll
      for (int nf=0; nf<4; nf++){
        int nl = wn*64 + nf*16 + lo;
        bf16x8 bY = *(const bf16x8*)&yt[cur][(nl*4 + (g ^ ((nl >> 1) & 3)))*8];
        #pragma unroll
        for (int mf=0; mf<4; mf++)
          acc[mf][nf] = __builtin_amdgcn_mfma_f32_16x16x32_bf16(aP[mf], bY, acc[mf][nf], 0,0,0);
      }
      __builtin_amdgcn_s_setprio(0);
      cur ^= 1;
    }
    short* outp = pp.p[kz];
    #pragma unroll
    for (int mf=0; mf<4; mf++){
      int row = m0 + wm*64 + mf*16 + g*4;
      #pragma unroll
      for (int nf=0; nf<4; nf++){
        int col = n0 + wn*64 + nf*16 + lo;
        #pragma unroll
        for (int r=0;r<4;r++)
          outp[(size_t)(row+r)*F + col] = f2b(acc[mf][nf][r]);
      }
    }
  } else {
    // ================= gather path (8-deep unroll) =================
    constexpr int LPR = F/8;
    constexpr int RPB = 512/LPR;
    int gid = blockIdx.x - nattn;
    int ts = t % LPR, rl = t / LPR;
    if (MODE == 0){
      constexpr int M = NN/RPB;
      int mat = gid / M;
      int blk = gid - mat*M;
      const int*   ptr  = mat ? ptr2  : ptr1;
      const int*   cidx = mat ? cidx2 : cidx1;
      const float* cval = mat ? cval2 : cval1;
      short* outb = mat ? so2 : so1;
      int r = blk*RPB + rl;
      const bf16x8* Y8 = (const bf16x8*)g1;
      int p0 = ptr[r], p1 = ptr[r+1];
      float a[8];
      #pragma unroll
      for (int j=0;j<8;j++) a[j]=0.f;
      int p = p0;
      for (; p+7 < p1; p += 8){
        int   c[8]; float v[8]; bf16x8 x[8];
        #pragma unroll
        for (int q=0;q<8;q++){ c[q]=cidx[p+q]; v[q]=cval[p+q]; }
        #pragma unroll
        for (int q=0;q<8;q++) x[q] = Y8[(size_t)c[q]*LPR + ts];
        #pragma unroll
        for (int q=0;q<8;q++)
          #pragma unroll
          for (int j=0;j<8;j++) a[j] += v[q]*b2f((unsigned short)x[q][j]);
      }
      for (; p < p1; ++p){
        int c0 = cidx[p]; float v0 = cval[p];
        bf16x8 x0 = Y8[(size_t)c0*LPR + ts];
        #pragma unroll
        for (int j=0;j<8;j++) a[j] += v0*b2f((unsigned short)x0[j]);
      }
      bf16x8 o;
      #pragma unroll
      for (int j=0;j<8;j++) o[j] = f2b(a[j]);
      ((bf16x8*)outb)[(size_t)r*LPR + ts] = o;
    } else {
      int r = gid*RPB + rl;
      const bf16x8* Xa = (const bf16x8*)g1;
      const bf16x8* Xb = (const bf16x8*)g2;
      float a[8];
      #pragma unroll
      for (int j=0;j<8;j++) a[j]=0.f;
      {
        int p0 = ptr1[r], p1 = ptr1[r+1];
        int p = p0;
        for (; p+7 < p1; p += 8){
          int   c[8]; float v[8]; bf16x8 x[8];
          #pragma unroll
          for (int q=0;q<8;q++){ c[q]=cidx1[p+q]; v[q]=cval1[p+q]; }
          #pragma unroll
          for (int q=0;q<8;q++) x[q] = Xa[(size_t)c[q]*LPR + ts];
          #pragma unroll
          for (int q=0;q<8;q++)
            #pragma unroll
            for (int j=0;j<8;j++) a[j] += v[q]*b2f((unsigned short)x[q][j]);
        }
        for (; p < p1; ++p){
          int c0 = cidx1[p]; float v0 = cval1[p];
          bf16x8 x0 = Xa[(size_t)c0*LPR + ts];
          #pragma unroll
          for (int j=0;j<8;j++) a[j] += v0*b2f((unsigned short)x0[j]);
        }
      }
      {
        int p0 = ptr2[r], p1 = ptr2[r+1];
        int p = p0;
        for (; p+7 < p1; p += 8){
          int   c[8]; float v[8]; bf16x8 x[8];
          #pragma unroll
          for (int q=0;q<8;q++){ c[q]=cidx2[p+q]; v[q]=cval2[p+q]; }
          #pragma unroll
          for (int q=0;q<8;q++) x[q] = Xb[(size_t)c[q]*LPR + ts];
          #pragma unroll
          for (int q=0;q<8;q++)
            #pragma unroll
            for (int j=0;j<8;j++) a[j] += v[q]*b2f((unsigned short)x[q][j]);
        }
        for (; p < p1; ++p){
          int c0 = cidx2[p]; float v0 = cval2[p];
          bf16x8 x0 = Xb[(size_t)c0*LPR + ts];
          #pragma unroll
          for (int j=0;j<8;j++) a[j] += v0*b2f((unsigned short)x0[j]);
        }
      }
      bf16x8 sa = Xa[(size_t)r*LPR + ts];
      bf16x8 sbx = Xb[(size_t)r*LPR + ts];
      bf16x8 yv = ((const bf16x8*)gy)[(size_t)r*LPR + ts];
      bf16x8 ob;
      #pragma unroll
      for (int j=0;j<8;j++)
        ob[j] = f2b(2.f*a[j] + b2f((unsigned short)sa[j]) + b2f((unsigned short)sbx[j]) - b2f((unsigned short)yv[j]));
      ((bf16x8*)Tb)[(size_t)r*LPR + ts] = ob;
    }
  }
}

// ---------------- layer-1 head (MFMA, 4 partials, bf16 T): H=relu((T+Σp)W1), + layer-2 Yt ----------------
__global__ __launch_bounds__(512) void k_headm_mfma(
    const short* __restrict__ Tb, P8s parts, const short* __restrict__ W1t,
    const float* __restrict__ sbv, short* __restrict__ Hb, short* __restrict__ Yt)
{
  __shared__ __align__(16) short hl[128*136];
  __shared__ float rsl[128];
  int t = threadIdx.x;
  int j0 = blockIdx.x*128, b = blockIdx.y;
  for (int u = t; u < 1024; u += 512){
    int row = u >> 3, c = u & 7;
    size_t base = (size_t)(j0+row)*512 + b*64 + c*8;
    bf16x8 tb = *(const bf16x8*)(Tb + base);
    float v[8];
    #pragma unroll
    for (int q=0;q<8;q++) v[q] = b2f((unsigned short)tb[q]);
    #pragma unroll
    for (int j=0;j<4;j++){
      bf16x8 p = *(const bf16x8*)(parts.p[j] + base);
      #pragma unroll
      for (int q=0;q<8;q++) v[q] += b2f((unsigned short)p[q]);
    }
    bf16x8 o;
    #pragma unroll
    for (int q=0;q<8;q++) o[q] = f2b(v[q]);
    *(bf16x8*)&hl[(row*8 + (c ^ (row & 7)))*8] = o;
  }
  if (t < 128) rsl[t] = 1.0f / sbv[j0 + t];
  __syncthreads();
  int w = t >> 6, l = t & 63, lo = l & 15, g = l >> 4;
  int arow = w*16 + lo;
  f32x4 acc[8];
  #pragma unroll
  for (int nf=0;nf<8;nf++) acc[nf] = (f32x4){0.f,0.f,0.f,0.f};
  #pragma unroll
  for (int ks=0; ks<2; ks++){
    bf16x8 aA = *(const bf16x8*)&hl[(arow*8 + ((ks*4+g) ^ (arow & 7)))*8];
    #pragma unroll
    for (int nf=0; nf<8; nf++){
      bf16x8 bW = *(const bf16x8*)(W1t + (size_t)(nf*16+lo)*64 + ks*32 + g*8);
      acc[nf] = __builtin_amdgcn_mfma_f32_16x16x32_bf16(aA, bW, acc[nf], 0,0,0);
    }
  }
  __syncthreads();
  int m = w*16 + g*4;
  #pragma unroll
  for (int nf=0; nf<8; nf++){
    int o = nf*16 + lo;
    #pragma unroll
    for (int r=0;r<4;r++){
      short hv = f2b(fmaxf(acc[nf][r], 0.f));
      hl[o*136 + m + r] = hv;
      Hb[(size_t)(j0+m+r)*1024 + b*128 + o] = hv;
    }
  }
  __syncthreads();
  for (int u = t; u < 2048; u += 512){
    int o = u >> 4, m8 = (u & 15)*8;
    bf16x8 hv = *(const bf16x8*)&hl[o*136 + m8];
    bf16x8 ov;
    #pragma unroll
    for (int q=0;q<8;q++) ov[q] = f2b(b2f((unsigned short)hv[q]) * rsl[m8+q]);
    *(bf16x8*)(Yt + (size_t)(b*128+o)*NN + j0 + m8) = ov;
  }
}

// ---------------- layer-2 head (MFMA, 2 partials, bf16 T) with fused node-mean ----------------
__global__ __launch_bounds__(512) void k_heads_mfma(
    const short* __restrict__ Tb, P8s parts, const short* __restrict__ W2t,
    float* __restrict__ out)
{
  __shared__ __align__(16) short al[128*16*8];
  __shared__ float red[8*128];
  int t = threadIdx.x;
  int j0 = blockIdx.x*128, b = blockIdx.y;
  for (int u = t; u < 2048; u += 512){
    int row = u >> 4, c = u & 15;
    size_t base = (size_t)(j0+row)*1024 + b*128 + c*8;
    bf16x8 tb = *(const bf16x8*)(Tb + base);
    float v[8];
    #pragma unroll
    for (int q=0;q<8;q++) v[q] = b2f((unsigned short)tb[q]);
    #pragma unroll
    for (int j=0;j<2;j++){
      bf16x8 p = *(const bf16x8*)(parts.p[j] + base);
      #pragma unroll
      for (int q=0;q<8;q++) v[q] += b2f((unsigned short)p[q]);
    }
    bf16x8 o;
    #pragma unroll
    for (int q=0;q<8;q++) o[q] = f2b(v[q]);
    *(bf16x8*)&al[(row*16 + (c ^ (row & 7)))*8] = o;
  }
  __syncthreads();
  int w = t >> 6, l = t & 63, lo = l & 15, g = l >> 4;
  int arow = w*16 + lo;
  f32x4 acc[8];
  #pragma unroll
  for (int nf=0;nf<8;nf++) acc[nf] = (f32x4){0.f,0.f,0.f,0.f};
  #pragma unroll
  for (int ks=0; ks<4; ks++){
    bf16x8 aA = *(const bf16x8*)&al[(arow*16 + ((ks*4+g) ^ (arow & 7)))*8];
    #pragma unroll
    for (int nf=0; nf<8; nf++){
      bf16x8 bW = *(const bf16x8*)(W2t + (size_t)(nf*16+lo)*128 + ks*32 + g*8);
      acc[nf] = __builtin_amdgcn_mfma_f32_16x16x32_bf16(aA, bW, acc[nf], 0,0,0);
    }
  }
  #pragma unroll
  for (int nf=0; nf<8; nf++){
    float s = fmaxf(acc[nf][0],0.f) + fmaxf(acc[nf][1],0.f)
            + fmaxf(acc[nf][2],0.f) + fmaxf(acc[nf][3],0.f);
    s += __shfl_xor(s, 16);
    s += __shfl_xor(s, 32);
    if (g == 0) red[w*128 + nf*16 + lo] = s;
  }
  __syncthreads();
  if (t < 128){
    float tot = 0.f;
    #pragma unroll
    for (int ww=0; ww<8; ww++) tot += red[ww*128 + t];
    atomicAdd(&out[b*128 + t], tot * (1.0f/8192.0f));
  }
}

// ---------------- launcher ----------------
extern "C" void kernel_launch(void* const* d_in, const int* in_sizes, int n_in,
                              void* d_out, int out_size, void* d_ws, size_t ws_size,
                              hipStream_t stream){
  const int*   A1i = (const int*)d_in[0];
  const float* A1v = (const float*)d_in[1];
  const int*   A2i = (const int*)d_in[2];
  const float* A2v = (const float*)d_in[3];
  const float* X   = (const float*)d_in[4];
  const float* Z   = (const float*)d_in[5];
  const float* W1  = (const float*)d_in[6];
  const float* W2  = (const float*)d_in[7];
  float* out = (float*)d_out;

  char* w = (char*)d_ws;
  size_t off = 0;
  auto alloc = [&](size_t b)->char* {
    char* p = w + off;
    off += (b + 1023) & ~(size_t)1023;
    return p;
  };
  const size_t MB = 1024*1024;
  float* sb    = (float*)alloc(NN*4);
  int*   ptr1  = (int*)  alloc((NN+1)*4);
  int*   ptr2  = (int*)  alloc((NN+1)*4);
  int*   cnt   = (int*)  alloc(2*NN*4);
  int*   cur1  = (int*)  alloc(NN*4);
  int*   cur2  = (int*)  alloc(NN*4);
  int*   cidx1 = (int*)  alloc(NNZE*4);
  float* cval1 = (float*)alloc(NNZE*4);
  int*   cidx2 = (int*)  alloc(NNZE*4);
  float* cval2 = (float*)alloc(NNZE*4);
  short* Zbf   = (short*)alloc((size_t)NN*64*2);
  short* W1t   = (short*)alloc(128*64*2);
  short* W2t   = (short*)alloc(128*128*2);
  short* XT1b  = (short*)alloc((size_t)NN*512*2);
  short* BUFA  = (short*)alloc((size_t)NN*1024*2);
  short* BUFB  = (short*)alloc((size_t)NN*1024*2);
  short* HTb   = (short*)alloc((size_t)NN*1024*2);
  short* YS    = (short*)alloc((size_t)NN*1024*2);
  short* T1b   = (short*)alloc((size_t)NN*512*2);    // bf16
  short* T2b   = (short*)alloc((size_t)NN*1024*2);   // bf16
  char*  PART  = alloc((size_t)32*MB);
  (void)ws_size;
  int* cnt1 = cnt;
  int* cnt2 = cnt + NN;

  // prep chain
  hipMemsetAsync(cnt, 0, 2*NN*4, stream);
  hipMemsetAsync(sb, 0, NN*4, stream);
  hipMemsetAsync(out, 0, 1024*4, stream);
  k_pre1<<<dim3(NNZE/256, 3), 256, 0, stream>>>(A1i, A2i, cnt1, cnt2, Z, Zbf);
  k_scan2<<<2, 1024, 0, stream>>>(cnt1, cnt2, ptr1, ptr2, cur1, cur2);
  k_pre3<<<5122, 512, 0, stream>>>(A1i, A1v, A2i, A2v, cur1, cur2,
                                   cidx1, cval1, cidx2, cval2,
                                   Zbf, sb, X, XT1b, W1, W2, W1t, W2t);
  k_scaleb<<<512*NN/4/256, 256, 0, stream>>>(X, sb, YS);

  // ---- layer 1 (F=512, attn kz=4, 2 slices/launch = 256 attn blocks) ----
  P8s pp1{};
  for (int i=0;i<4;i++) pp1.p[i] = (short*)(PART + (size_t)i*8*MB);
  k_fused<512,0><<<256 + 2048, 512, 0, stream>>>(Zbf, YS, pp1, NN/4, 0, 256,
      ptr1, cidx1, cval1, ptr2, cidx2, cval2,
      XT1b, nullptr, nullptr, BUFA, BUFB, nullptr);
  k_fused<512,1><<<256 + 1024, 512, 0, stream>>>(Zbf, YS, pp1, NN/4, 2, 256,
      ptr1, cidx1, cval1, ptr2, cidx2, cval2,
      BUFA, BUFB, XT1b, nullptr, nullptr, T1b);
  k_headm_mfma<<<dim3(NN/128, 8), 512, 0, stream>>>(T1b, pp1, W1t, sb, HTb, YS);

  // ---- layer 2 (F=1024, attn kz=2, 1 slice/launch = 256 attn blocks) ----
  P8s pp2{};
  pp2.p[0] = (short*)PART;
  pp2.p[1] = (short*)(PART + (size_t)16*MB);
  k_fused<1024,0><<<256 + 4096, 512, 0, stream>>>(Zbf, YS, pp2, NN/2, 0, 256,
      ptr1, cidx1, cval1, ptr2, cidx2, cval2,
      HTb, nullptr, nullptr, BUFA, BUFB, nullptr);
  k_fused<1024,1><<<256 + 2048, 512, 0, stream>>>(Zbf, YS, pp2, NN/2, 1, 256,
      ptr1, cidx1, cval1, ptr2, cidx2, cval2,
      BUFA, BUFB, HTb, nullptr, nullptr, T2b);
  k_heads_mfma<<<dim3(NN/128, 8), 512, 0, stream>>>(T2b, pp2, W2t, out);
}